// Round 19
// baseline (179.822 us; speedup 1.0000x reference)
//
#include <hip/hip_runtime.h>
#include <hip/hip_bf16.h>

typedef __attribute__((ext_vector_type(4))) float f32x4;
typedef __attribute__((ext_vector_type(8))) short bf16x8;

#define DEV __device__ __forceinline__

DEV unsigned short f2bf(float f) {
  union { float f; unsigned int u; } v; v.f = f;
  unsigned int r = v.u + 0x7fffu + ((v.u >> 16) & 1u);
  return (unsigned short)(r >> 16);
}

DEV float bf2f(unsigned short u) {
  union { unsigned int u; float f; } v; v.u = ((unsigned int)u) << 16; return v.f;
}

DEV short2 pkbf(float a, float b) {
  float2 t; t.x = a; t.y = b;
  __hip_bfloat162 h = __float22bfloat162_rn(t);
  union { __hip_bfloat162 h; short2 s; } u; u.h = h; return u.s;
}

DEV int pk2i(float a, float b) {
  union { short2 s; int i; } u; u.s = pkbf(a, b); return u.i;
}

DEV bf16x8 cvt8(float4 u, float4 v) {
  short2 a = pkbf(u.x, u.y), b = pkbf(u.z, u.w), c = pkbf(v.x, v.y), d = pkbf(v.z, v.w);
  bf16x8 r;
  r[0] = a.x; r[1] = a.y; r[2] = b.x; r[3] = b.y;
  r[4] = c.x; r[5] = c.y; r[6] = d.x; r[7] = d.y;
  return r;
}

// tanh-approx gelu via sigmoid form, fast rcp
DEV float gelu_fast(float v) {
  float u = 1.5957691216057308f * v * (1.0f + 0.044715f * v * v);
  return v * __builtin_amdgcn_rcpf(1.0f + __expf(-u));
}

// window token row -> natural (b,t,h,w) flat token index (handles roll both ways)
DEV size_t winmap(int row) {
  int wIdx = row >> 7, n = row & 127;
  int b = wIdx >> 8, widx = wIdx & 255;
  int t = (((widx >> 6) * 2 + (n >> 6)) + 1) & 7;
  int h = ((((widx >> 3) & 7) * 8 + ((n >> 3) & 7)) + 4) & 63;
  int w = (((widx & 7) * 8 + (n & 7)) + 4) & 63;
  return (size_t)(((b * 8 + t) * 64 + h) * 64 + w);
}

// region id for shifted-window mask: tokens in different regions get -100
DEV int reg3(int tw, int hw, int ww, int n) {
  int ts = tw * 2 + (n >> 6);
  int hs = hw * 8 + ((n >> 3) & 7);
  int wsv = ww * 8 + (n & 7);
  int rt = (ts >= 7) ? 2 : ((ts >= 6) ? 1 : 0);
  int rh = (hs >= 60) ? 2 : ((hs >= 56) ? 1 : 0);
  int rw = (wsv >= 60) ? 2 : ((wsv >= 56) ? 1 : 0);
  return rt * 9 + rh * 3 + rw;
}

DEV void gload16(const unsigned short* g, unsigned short* lds) {
  __builtin_amdgcn_global_load_lds(
      (const __attribute__((address_space(1))) unsigned int*)g,
      (__attribute__((address_space(3))) unsigned int*)lds, 16, 0, 0);
}

// ---------------- prep: cast weights to bf16, build rel-pos bias in TRANSPOSED-frag layout ----
// For swapped QK^T (S^T fragments): lane (wave, lrow, lk) needs bias[q=wave*16+lrow][kcol=
// 16tc+4lk+j] at b6 + h*16384 + wave*2048 + lane*32 + tc*4 + j  (lane = lk*16+lrow).
__global__ __launch_bounds__(256) void k_prep(
    const float* __restrict__ qkv_w, const float* __restrict__ proj_w,
    const float* __restrict__ fc1_w, const float* __restrict__ fc2_w,
    const float* __restrict__ rpb_t, const int* __restrict__ rpb_i,
    unsigned short* __restrict__ wq, unsigned short* __restrict__ wp,
    unsigned short* __restrict__ w1, unsigned short* __restrict__ w2,
    float* __restrict__ b6) {
  int i = blockIdx.x * 256 + threadIdx.x;
  if (i < 110592) wq[i] = f2bf(qkv_w[i]);
  if (i < 36864)  wp[i] = f2bf(proj_w[i]);
  if (i < 147456) { w1[i] = f2bf(fc1_w[i]); w2[i] = f2bf(fc2_w[i]); }
  if (i < 16384) {
    int q = i >> 7, col = i & 127;
    int idx = rpb_i[i];
    int dest = (q >> 4) * 2048 + ((col >> 2) & 3) * 512 + (q & 15) * 32 +
               (col >> 4) * 4 + (col & 3);
    #pragma unroll
    for (int h = 0; h < 6; ++h) b6[h * 16384 + dest] = rpb_t[idx * 6 + h];
  }
}

// ---------------- qkv GEMM: gather x (roll+window) fused into A staging ----------------
__global__ __launch_bounds__(256) void k_qkv(
    const float* __restrict__ x, const unsigned short* __restrict__ Bm,
    const float* __restrict__ bias, unsigned short* __restrict__ outb) {
  __shared__ char smem[40960];
  float* As = (float*)smem;                      // [128 rows][16 slots of 16B] swizzled
  unsigned short* Bs = (unsigned short*)(smem + 32768);
  unsigned short* Cs = (unsigned short*)smem;    // epilogue reuse, stride 72
  const int tid = threadIdx.x;
  const int wave = tid >> 6, lane = tid & 63;
  const int lin = ((int)blockIdx.x & 7) * 576 + ((int)blockIdx.x >> 3);
  const int mt = lin / 9, nt = lin - mt * 9;
  const int m0 = mt * 128, n0 = nt * 64;
  const int wr = wave >> 1, wc = wave & 1;
  const int l8 = lane >> 3, s8 = lane & 7;

  const float* aptr[8];
  #pragma unroll
  for (int i = 0; i < 8; ++i) {
    int row = wave * 32 + i * 4 + (lane >> 4);
    aptr[i] = x + winmap(m0 + row) * 192 + (((lane & 15) ^ (row & 15)) << 2);
  }

  f32x4 acc[4][2] = {};
  for (int kt = 0; kt < 192; kt += 64) {
    __syncthreads();
    #pragma unroll
    for (int i = 0; i < 8; ++i)
      gload16((const unsigned short*)(aptr[i] + kt), (unsigned short*)(As + (wave * 8 + i) * 256));
    #pragma unroll
    for (int j = 0; j < 2; ++j) {
      int c = wave * 2 + j;
      int row = c * 8 + l8;
      gload16(Bm + (size_t)(n0 + row) * 192 + kt + (s8 ^ l8) * 8, Bs + c * 512);
    }
    __syncthreads();

    #pragma unroll
    for (int kk = 0; kk < 2; ++kk) {
      bf16x8 af[4], bfr[2];
      #pragma unroll
      for (int mi = 0; mi < 4; ++mi) {
        int r = wr * 64 + mi * 16 + (lane & 15);
        int s0 = kk * 8 + (lane >> 4) * 2;
        float4 u = *(const float4*)(As + r * 64 + ((s0 ^ (r & 15)) << 2));
        float4 v = *(const float4*)(As + r * 64 + (((s0 + 1) ^ (r & 15)) << 2));
        af[mi] = cvt8(u, v);
      }
      #pragma unroll
      for (int ni = 0; ni < 2; ++ni) {
        int row = wc * 32 + ni * 16 + (lane & 15);
        int slot = (kk * 4 + (lane >> 4)) ^ (row & 7);
        bfr[ni] = *(const bf16x8*)(Bs + row * 64 + slot * 8);
      }
      #pragma unroll
      for (int mi = 0; mi < 4; ++mi)
        #pragma unroll
        for (int ni = 0; ni < 2; ++ni)
          acc[mi][ni] = __builtin_amdgcn_mfma_f32_16x16x32_bf16(af[mi], bfr[ni], acc[mi][ni], 0, 0, 0);
    }
  }

  __syncthreads();
  #pragma unroll
  for (int ni = 0; ni < 2; ++ni) {
    int coll = wc * 32 + ni * 16 + (lane & 15);
    float bb = bias[n0 + coll];
    #pragma unroll
    for (int mi = 0; mi < 4; ++mi) {
      int rbase = wr * 64 + mi * 16 + ((lane >> 4) << 2);
      #pragma unroll
      for (int j = 0; j < 4; ++j)
        Cs[(rbase + j) * 72 + coll] = f2bf(acc[mi][ni][j] + bb);
    }
  }
  __syncthreads();
  const int row = tid >> 1, hh = tid & 1;
  unsigned short* gb = outb + (size_t)(m0 + row) * 576 + n0 + hh * 32;
  #pragma unroll
  for (int s = 0; s < 4; ++s)
    *(bf16x8*)(gb + s * 8) = *(const bf16x8*)(Cs + row * 72 + hh * 32 + s * 8);
}

// ---------------- fused attention+proj v4: swapped QK^T, lane-local softmax, no Pl ------
// S^T = mfma(K,Q): lane holds P[q=wave*16+lrow][kc=16tc+4lk+j]. Softmax denominator =
// local adds + 2 shfl_xor. PV B-frag assembled by 4-lane shfl exchange (derived bijective).
// PV swapped: O^T = mfma(V^T, P). LDS: Kl 8K + Vt 8.5K + Os 10K + Wp 12K = 38.5K.
// 2 barriers/head (B1 stage-visible, B4 pre-overwrite).
DEV void stage_head(const unsigned short* qkv, size_t qbase, int h,
                    const unsigned short* wp, unsigned short* Kl,
                    unsigned short* Vt, unsigned short* Wp,
                    int tid, int wave, int lane) {
  {  // K rows, XOR-swizzled slots
    int row = tid >> 2, slot = tid & 3;
    int m = (row + (row >> 2)) & 3;
    *(bf16x8*)(Kl + row * 32 + ((slot ^ m) * 8)) =
        *(const bf16x8*)(qkv + qbase + (size_t)row * 576 + 192 + h * 32 + slot * 8);
  }
  {  // V transposed
    int vtok = tid & 127, slot = tid >> 7;
    bf16x8 v = *(const bf16x8*)(qkv + qbase + (size_t)vtok * 576 + 384 + h * 32 + slot * 8);
    #pragma unroll
    for (int j = 0; j < 8; ++j) Vt[(slot * 8 + j) * 136 + vtok] = (unsigned short)v[j];
  }
  {  // wp slice [192 out][32 in]
    int c = wave;
    int rg = c * 16 + (lane >> 2);
    gload16(wp + (size_t)rg * 192 + h * 32 + (((lane & 3) ^ ((rg >> 1) & 3)) * 8), Wp + c * 512);
    if (wave < 4) {
      int c2 = 8 + wave;
      int rg2 = c2 * 16 + (lane >> 2);
      gload16(wp + (size_t)rg2 * 192 + h * 32 + (((lane & 3) ^ ((rg2 >> 1) & 3)) * 8), Wp + c2 * 512);
    }
  }
}

__global__ __launch_bounds__(512, 4) void k_attnproj(
    const unsigned short* __restrict__ qkv, const float* __restrict__ bias6,
    const unsigned short* __restrict__ wp, const float* __restrict__ proj_b,
    const float* __restrict__ x, unsigned short* __restrict__ ybf) {
  __shared__ unsigned short Kl[128 * 32];
  __shared__ unsigned short Vt[32 * 136];
  __shared__ unsigned short Os[128 * 40];
  __shared__ unsigned short Wp[192 * 32];
  const int tid = threadIdx.x;
  const int wave = tid >> 6, lane = tid & 63;
  const int lrow = lane & 15, lk = lane >> 4;
  const int wIdx = ((int)blockIdx.x & 7) * 64 + ((int)blockIdx.x >> 3);
  const int widx = wIdx & 255;
  const int tw = widx >> 6, hw = (widx >> 3) & 7, ww = widx & 7;
  const size_t qbase = (size_t)wIdx * 73728;
  const float scale = 0.17677669529663687f;

  // q-row region (one per lane) + kcol-region match bits (h-invariant)
  const int rq = reg3(tw, hw, ww, wave * 16 + lrow);
  unsigned int mbits = 0;
  #pragma unroll
  for (int tc = 0; tc < 8; ++tc)
    #pragma unroll
    for (int j = 0; j < 4; ++j)
      mbits |= (unsigned int)(reg3(tw, hw, ww, 16 * tc + 4 * lk + j) == rq) << (tc * 4 + j);

  stage_head(qkv, qbase, 0, wp, Kl, Vt, Wp, tid, wave, lane);

  f32x4 oaccP[12] = {};
  for (int h = 0; h < 6; ++h) {
    __syncthreads();   // B1: stage(h) visible

    bf16x8 qf = *(const bf16x8*)(qkv + qbase + (size_t)(wave * 16 + lrow) * 576 +
                                 h * 32 + lk * 8);
    const float* bp = bias6 + h * 16384 + wave * 2048 + lane * 32;

    f32x4 o[2] = {};
    float psum = 0.f;
    #pragma unroll
    for (int ks = 0; ks < 4; ++ks) {
      // S^T fragments for tc=2ks, 2ks+1 (A=K, B=Q)
      f32x4 s0, s1;
      {
        int kr0 = (2 * ks) * 16 + lrow;
        int m0s = (kr0 + (kr0 >> 2)) & 3;
        bf16x8 kf0 = *(const bf16x8*)(Kl + kr0 * 32 + ((lk ^ m0s) * 8));
        int kr1 = (2 * ks + 1) * 16 + lrow;
        int m1s = (kr1 + (kr1 >> 2)) & 3;
        bf16x8 kf1 = *(const bf16x8*)(Kl + kr1 * 32 + ((lk ^ m1s) * 8));
        f32x4 z = {0.f, 0.f, 0.f, 0.f};
        s0 = __builtin_amdgcn_mfma_f32_16x16x32_bf16(kf0, qf, z, 0, 0, 0);
        s1 = __builtin_amdgcn_mfma_f32_16x16x32_bf16(kf1, qf, z, 0, 0, 0);
      }
      // bias + mask + exp (P row is lane-local)
      f32x4 bb0 = *(const f32x4*)(bp + (2 * ks) * 4);
      f32x4 bb1 = *(const f32x4*)(bp + (2 * ks + 1) * 4);
      #pragma unroll
      for (int j = 0; j < 4; ++j) {
        float m0v = ((mbits >> ((2 * ks) * 4 + j)) & 1) ? 0.0f : -100.0f;
        float m1v = ((mbits >> ((2 * ks + 1) * 4 + j)) & 1) ? 0.0f : -100.0f;
        s0[j] = __expf(fmaf(s0[j], scale, bb0[j] + m0v));
        s1[j] = __expf(fmaf(s1[j], scale, bb1[j] + m1v));
        psum += s0[j] + s1[j];
      }
      // pack + 4-lane exchange -> PV B-fragment (kc = 32ks + 8lk + 0..7)
      int A0 = pk2i(s0[0], s0[1]), A1 = pk2i(s0[2], s0[3]);
      int B0 = pk2i(s1[0], s1[1]), B1 = pk2i(s1[2], s1[3]);
      int base = (lk & 1) * 32 + lrow;
      int w0u = __shfl(A0, base),      w0v = __shfl(B0, base);
      int w1u = __shfl(A1, base),      w1v = __shfl(B1, base);
      int w2u = __shfl(A0, base + 16), w2v = __shfl(B0, base + 16);
      int w3u = __shfl(A1, base + 16), w3v = __shfl(B1, base + 16);
      union { int w[4]; bf16x8 v; } pb;
      int hi = lk >> 1;
      pb.w[0] = hi ? w0v : w0u;
      pb.w[1] = hi ? w1v : w1u;
      pb.w[2] = hi ? w2v : w2u;
      pb.w[3] = hi ? w3v : w3u;
      // PV: O^T[d][q] += V^T[d][kc] * P[q][kc]
      #pragma unroll
      for (int nc = 0; nc < 2; ++nc) {
        bf16x8 vb = *(const bf16x8*)(Vt + (nc * 16 + lrow) * 136 + ks * 32 + lk * 8);
        o[nc] = __builtin_amdgcn_mfma_f32_16x16x32_bf16(vb, pb.v, o[nc], 0, 0, 0);
      }
    }
    // denominator: local sum + reduce over lk-lanes (16, 32)
    psum += __shfl_xor(psum, 16);
    psum += __shfl_xor(psum, 32);
    float rinv = __builtin_amdgcn_rcpf(psum);

    // O^T -> Os[q][d] (wave-private rows; ushort4 writes)
    {
      int qrow = wave * 16 + lrow;
      #pragma unroll
      for (int nc = 0; nc < 2; ++nc) {
        short2 a = pkbf(o[nc][0] * rinv, o[nc][1] * rinv);
        short2 b = pkbf(o[nc][2] * rinv, o[nc][3] * rinv);
        ushort4 ov;
        ov.x = (unsigned short)a.x; ov.y = (unsigned short)a.y;
        ov.z = (unsigned short)b.x; ov.w = (unsigned short)b.y;
        *(ushort4*)(Os + qrow * 40 + nc * 16 + lk * 4) = ov;
      }
    }

    // proj partial: oaccP[ni] += O_h[16x32] @ wp_h^T
    {
      bf16x8 af = *(const bf16x8*)(Os + (wave * 16 + lrow) * 40 + lk * 8);
      #pragma unroll
      for (int ni = 0; ni < 12; ++ni) {
        int n = ni * 16 + lrow;
        bf16x8 bv = *(const bf16x8*)(Wp + n * 32 + ((lk ^ ((n >> 1) & 3)) * 8));
        oaccP[ni] = __builtin_amdgcn_mfma_f32_16x16x32_bf16(af, bv, oaccP[ni], 0, 0, 0);
      }
    }
    __syncthreads();   // B4: all reads of head h done
    if (h < 5) stage_head(qkv, qbase, h + 1, wp, Kl, Vt, Wp, tid, wave, lane);
  }

  // epilogue: ybf = bf16(proj + proj_b + x)  (winmap scatter)
  size_t gf[4];
  #pragma unroll
  for (int j = 0; j < 4; ++j)
    gf[j] = winmap(wIdx * 128 + wave * 16 + lk * 4 + j) * 192;
  #pragma unroll
  for (int ni = 0; ni < 12; ++ni) {
    int col = ni * 16 + lrow;
    float bb = proj_b[col];
    #pragma unroll
    for (int j = 0; j < 4; ++j) {
      size_t idx = gf[j] + col;
      ybf[idx] = f2bf(oaccP[ni][j] + bb + x[idx]);
    }
  }
}

// ---------------- fused MLP v4 (known-good 67.7us): out = x + gelu(y@w1^T+b1)@w2^T + b2 ----
DEV void stage_w(const unsigned short* w1, const unsigned short* w2, int hb,
                 char* smem, int buf, int wave, int lane) {
  unsigned short* d1 = (unsigned short*)(smem + buf * 12288);
  unsigned short* d2 = (unsigned short*)(smem + 24576 + buf * 12288);
  const int l8 = lane >> 3, s8 = lane & 7;
  {
    int c = wave, p = c >> 2, q = c & 3;
    gload16(w1 + (size_t)(hb + q * 8 + l8) * 192 + p * 64 + ((s8 ^ l8) * 8), d1 + c * 512);
  }
  if (wave < 4) {
    int c = 8 + wave, p = c >> 2, q = c & 3;
    gload16(w1 + (size_t)(hb + q * 8 + l8) * 192 + p * 64 + ((s8 ^ l8) * 8), d1 + c * 512);
  }
  {
    int c = wave;
    int rg = c * 16 + (lane >> 2);
    gload16(w2 + (size_t)rg * 768 + hb + (((lane & 3) ^ ((rg >> 1) & 3)) * 8), d2 + c * 512);
  }
  if (wave < 4) {
    int c = 8 + wave;
    int rg = c * 16 + (lane >> 2);
    gload16(w2 + (size_t)rg * 768 + hb + (((lane & 3) ^ ((rg >> 1) & 3)) * 8), d2 + c * 512);
  }
}

__global__ __launch_bounds__(512, 4) void k_mlp(
    const unsigned short* __restrict__ y, const unsigned short* __restrict__ w1,
    const float* __restrict__ b1, const unsigned short* __restrict__ w2,
    const float* __restrict__ b2, const float* __restrict__ xin,
    float* __restrict__ out) {
  __shared__ char smem[57344];
  unsigned short* Hs = (unsigned short*)(smem + 49152);   // [128][32]
  const int tid = threadIdx.x;
  const int wave = tid >> 6, lane = tid & 63;
  const int lrow = lane & 15, lk = lane >> 4;
  const int m0 = (int)blockIdx.x * 128;
  const int tok = wave * 16 + lrow;
  const int tq = (lrow >> 1) & 3;

  bf16x8 yfr[6];
  {
    const unsigned short* yp = y + (size_t)(m0 + tok) * 192 + lk * 8;
    #pragma unroll
    for (int kk = 0; kk < 6; ++kk) yfr[kk] = *(const bf16x8*)(yp + kk * 32);
  }

  stage_w(w1, w2, 0, smem, 0, wave, lane);
  stage_w(w1, w2, 32, smem, 1, wave, lane);
  __syncthreads();

  f32x4 oacc[12] = {};
  for (int c = 0; c < 24; ++c) {
    const int hb = c * 32;
    unsigned short* w1b = (unsigned short*)(smem + (c & 1) * 12288);
    unsigned short* w2b = (unsigned short*)(smem + 24576 + (c & 1) * 12288);

    f32x4 hacc[2] = {};
    #pragma unroll
    for (int kk = 0; kk < 6; ++kk) {
      int p = kk >> 1, sc = (kk & 1) * 4;
      #pragma unroll
      for (int hi = 0; hi < 2; ++hi) {
        bf16x8 av = *(const bf16x8*)(w1b + p * 2048 + (hi * 16 + lrow) * 64 +
                                     (((sc + lk) ^ (lrow & 7)) * 8));
        hacc[hi] = __builtin_amdgcn_mfma_f32_16x16x32_bf16(av, yfr[kk], hacc[hi], 0, 0, 0);
      }
    }

    #pragma unroll
    for (int hi = 0; hi < 2; ++hi) {
      float4 bb = *(const float4*)(b1 + hb + hi * 16 + lk * 4);
      short2 p01 = pkbf(gelu_fast(hacc[hi][0] + bb.x), gelu_fast(hacc[hi][1] + bb.y));
      short2 p23 = pkbf(gelu_fast(hacc[hi][2] + bb.z), gelu_fast(hacc[hi][3] + bb.w));
      ushort4 o;
      o.x = (unsigned short)p01.x; o.y = (unsigned short)p01.y;
      o.z = (unsigned short)p23.x; o.w = (unsigned short)p23.y;
      int g = hi * 4 + lk;
      *(ushort4*)(Hs + tok * 32 + (((g >> 1) ^ tq) * 8) + (g & 1) * 4) = o;
    }

    {
      bf16x8 af = *(const bf16x8*)(Hs + tok * 32 + ((lk ^ tq) * 8));
      #pragma unroll
      for (int ni = 0; ni < 12; ++ni) {
        int n = ni * 16 + lrow;
        bf16x8 bv = *(const bf16x8*)(w2b + n * 32 + ((lk ^ ((n >> 1) & 3)) * 8));
        oacc[ni] = __builtin_amdgcn_mfma_f32_16x16x32_bf16(af, bv, oacc[ni], 0, 0, 0);
      }
    }

    __syncthreads();
    if (c < 22) stage_w(w1, w2, hb + 64, smem, c & 1, wave, lane);
  }

  #pragma unroll
  for (int ni = 0; ni < 12; ++ni) {
    int col = ni * 16 + lrow;
    float bb = b2[col];
    #pragma unroll
    for (int j = 0; j < 4; ++j) {
      size_t idx = (size_t)(m0 + wave * 16 + lk * 4 + j) * 192 + col;
      out[idx] = xin[idx] + oacc[ni][j] + bb;
    }
  }
}

// ---------------- launch ----------------
extern "C" void kernel_launch(void* const* d_in, const int* in_sizes, int n_in,
                              void* d_out, int out_size, void* d_ws, size_t ws_size,
                              hipStream_t stream) {
  const float* x      = (const float*)d_in[0];
  const float* qkv_w  = (const float*)d_in[2];
  const float* qkv_b  = (const float*)d_in[3];
  const float* proj_w = (const float*)d_in[4];
  const float* proj_b = (const float*)d_in[5];
  const float* rpb_t  = (const float*)d_in[6];
  const int*   rpb_i  = (const int*)d_in[7];
  const float* fc1_w  = (const float*)d_in[8];
  const float* fc1_b  = (const float*)d_in[9];
  const float* fc2_w  = (const float*)d_in[10];
  const float* fc2_b  = (const float*)d_in[11];
  float* out = (float*)d_out;
  char* ws = (char*)d_ws;

  unsigned short* qkv = (unsigned short*)(ws + 0);          // 65536x576 bf16
  unsigned short* ybf = (unsigned short*)(ws + 100663296);  // 65536x192 bf16
  unsigned short* wq  = (unsigned short*)(ws + 125829120);
  unsigned short* wp  = (unsigned short*)(ws + 126050304);
  unsigned short* w1  = (unsigned short*)(ws + 126124032);
  unsigned short* w2  = (unsigned short*)(ws + 126418944);
  float*          b6  = (float*)(ws + 126713856);

  k_prep<<<576, 256, 0, stream>>>(qkv_w, proj_w, fc1_w, fc2_w, rpb_t, rpb_i, wq, wp, w1, w2, b6);
  k_qkv<<<4608, 256, 0, stream>>>(x, wq, qkv_b, qkv);
  k_attnproj<<<512, 512, 0, stream>>>(qkv, b6, wp, proj_b, x, ybf);
  k_mlp<<<512, 512, 0, stream>>>(ybf, w1, fc1_b, w2, fc2_b, x, out);
}

// Round 20
// 174.665 us; speedup vs baseline: 1.0295x; 1.0295x over previous
//
#include <hip/hip_runtime.h>
#include <hip/hip_bf16.h>

typedef __attribute__((ext_vector_type(4))) float f32x4;
typedef __attribute__((ext_vector_type(8))) short bf16x8;

#define DEV __device__ __forceinline__

DEV unsigned short f2bf(float f) {
  union { float f; unsigned int u; } v; v.f = f;
  unsigned int r = v.u + 0x7fffu + ((v.u >> 16) & 1u);
  return (unsigned short)(r >> 16);
}

DEV float bf2f(unsigned short u) {
  union { unsigned int u; float f; } v; v.u = ((unsigned int)u) << 16; return v.f;
}

DEV short2 pkbf(float a, float b) {
  float2 t; t.x = a; t.y = b;
  __hip_bfloat162 h = __float22bfloat162_rn(t);
  union { __hip_bfloat162 h; short2 s; } u; u.h = h; return u.s;
}

DEV bf16x8 cvt8(float4 u, float4 v) {
  short2 a = pkbf(u.x, u.y), b = pkbf(u.z, u.w), c = pkbf(v.x, v.y), d = pkbf(v.z, v.w);
  bf16x8 r;
  r[0] = a.x; r[1] = a.y; r[2] = b.x; r[3] = b.y;
  r[4] = c.x; r[5] = c.y; r[6] = d.x; r[7] = d.y;
  return r;
}

// tanh-approx gelu via sigmoid form, fast rcp
DEV float gelu_fast(float v) {
  float u = 1.5957691216057308f * v * (1.0f + 0.044715f * v * v);
  return v * __builtin_amdgcn_rcpf(1.0f + __expf(-u));
}

// window token row -> natural (b,t,h,w) flat token index (handles roll both ways)
DEV size_t winmap(int row) {
  int wIdx = row >> 7, n = row & 127;
  int b = wIdx >> 8, widx = wIdx & 255;
  int t = (((widx >> 6) * 2 + (n >> 6)) + 1) & 7;
  int h = ((((widx >> 3) & 7) * 8 + ((n >> 3) & 7)) + 4) & 63;
  int w = (((widx & 7) * 8 + (n & 7)) + 4) & 63;
  return (size_t)(((b * 8 + t) * 64 + h) * 64 + w);
}

// region id for shifted-window mask: tokens in different regions get -100
DEV int reg3(int tw, int hw, int ww, int n) {
  int ts = tw * 2 + (n >> 6);
  int hs = hw * 8 + ((n >> 3) & 7);
  int wsv = ww * 8 + (n & 7);
  int rt = (ts >= 7) ? 2 : ((ts >= 6) ? 1 : 0);
  int rh = (hs >= 60) ? 2 : ((hs >= 56) ? 1 : 0);
  int rw = (wsv >= 60) ? 2 : ((wsv >= 56) ? 1 : 0);
  return rt * 9 + rh * 3 + rw;
}

DEV void gload16(const unsigned short* g, unsigned short* lds) {
  __builtin_amdgcn_global_load_lds(
      (const __attribute__((address_space(1))) unsigned int*)g,
      (__attribute__((address_space(3))) unsigned int*)lds, 16, 0, 0);
}

// ---------------- prep: cast weights to bf16, build rel-pos bias in MFMA-fragment layout ----
__global__ __launch_bounds__(256) void k_prep(
    const float* __restrict__ qkv_w, const float* __restrict__ proj_w,
    const float* __restrict__ fc1_w, const float* __restrict__ fc2_w,
    const float* __restrict__ rpb_t, const int* __restrict__ rpb_i,
    unsigned short* __restrict__ wq, unsigned short* __restrict__ wp,
    unsigned short* __restrict__ w1, unsigned short* __restrict__ w2,
    float* __restrict__ b6) {
  int i = blockIdx.x * 256 + threadIdx.x;
  if (i < 110592) wq[i] = f2bf(qkv_w[i]);
  if (i < 36864)  wp[i] = f2bf(proj_w[i]);
  if (i < 147456) { w1[i] = f2bf(fc1_w[i]); w2[i] = f2bf(fc2_w[i]); }
  if (i < 16384) {
    int row = i >> 7, col = i & 127;
    int idx = rpb_i[i];
    int dest = (row >> 4) * 2048 + (((row >> 2) & 3) * 16 + (col & 15)) * 32 +
               (col >> 4) * 4 + (row & 3);
    #pragma unroll
    for (int h = 0; h < 6; ++h) b6[h * 16384 + dest] = rpb_t[idx * 6 + h];
  }
}

// ---------------- qkv GEMM: gather x (roll+window) fused into A staging ----------------
__global__ __launch_bounds__(256) void k_qkv(
    const float* __restrict__ x, const unsigned short* __restrict__ Bm,
    const float* __restrict__ bias, unsigned short* __restrict__ outb) {
  __shared__ char smem[40960];
  float* As = (float*)smem;                      // [128 rows][16 slots of 16B] swizzled
  unsigned short* Bs = (unsigned short*)(smem + 32768);
  unsigned short* Cs = (unsigned short*)smem;    // epilogue reuse, stride 72
  const int tid = threadIdx.x;
  const int wave = tid >> 6, lane = tid & 63;
  const int lin = ((int)blockIdx.x & 7) * 576 + ((int)blockIdx.x >> 3);
  const int mt = lin / 9, nt = lin - mt * 9;
  const int m0 = mt * 128, n0 = nt * 64;
  const int wr = wave >> 1, wc = wave & 1;
  const int l8 = lane >> 3, s8 = lane & 7;

  const float* aptr[8];
  #pragma unroll
  for (int i = 0; i < 8; ++i) {
    int row = wave * 32 + i * 4 + (lane >> 4);
    aptr[i] = x + winmap(m0 + row) * 192 + (((lane & 15) ^ (row & 15)) << 2);
  }

  f32x4 acc[4][2] = {};
  for (int kt = 0; kt < 192; kt += 64) {
    __syncthreads();
    #pragma unroll
    for (int i = 0; i < 8; ++i)
      gload16((const unsigned short*)(aptr[i] + kt), (unsigned short*)(As + (wave * 8 + i) * 256));
    #pragma unroll
    for (int j = 0; j < 2; ++j) {
      int c = wave * 2 + j;
      int row = c * 8 + l8;
      gload16(Bm + (size_t)(n0 + row) * 192 + kt + (s8 ^ l8) * 8, Bs + c * 512);
    }
    __syncthreads();

    #pragma unroll
    for (int kk = 0; kk < 2; ++kk) {
      bf16x8 af[4], bfr[2];
      #pragma unroll
      for (int mi = 0; mi < 4; ++mi) {
        int r = wr * 64 + mi * 16 + (lane & 15);
        int s0 = kk * 8 + (lane >> 4) * 2;
        float4 u = *(const float4*)(As + r * 64 + ((s0 ^ (r & 15)) << 2));
        float4 v = *(const float4*)(As + r * 64 + (((s0 + 1) ^ (r & 15)) << 2));
        af[mi] = cvt8(u, v);
      }
      #pragma unroll
      for (int ni = 0; ni < 2; ++ni) {
        int row = wc * 32 + ni * 16 + (lane & 15);
        int slot = (kk * 4 + (lane >> 4)) ^ (row & 7);
        bfr[ni] = *(const bf16x8*)(Bs + row * 64 + slot * 8);
      }
      #pragma unroll
      for (int mi = 0; mi < 4; ++mi)
        #pragma unroll
        for (int ni = 0; ni < 2; ++ni)
          acc[mi][ni] = __builtin_amdgcn_mfma_f32_16x16x32_bf16(af[mi], bfr[ni], acc[mi][ni], 0, 0, 0);
    }
  }

  __syncthreads();
  #pragma unroll
  for (int ni = 0; ni < 2; ++ni) {
    int coll = wc * 32 + ni * 16 + (lane & 15);
    float bb = bias[n0 + coll];
    #pragma unroll
    for (int mi = 0; mi < 4; ++mi) {
      int rbase = wr * 64 + mi * 16 + ((lane >> 4) << 2);
      #pragma unroll
      for (int j = 0; j < 4; ++j)
        Cs[(rbase + j) * 72 + coll] = f2bf(acc[mi][ni][j] + bb);
    }
  }
  __syncthreads();
  const int row = tid >> 1, hh = tid & 1;
  unsigned short* gb = outb + (size_t)(m0 + row) * 576 + n0 + hh * 32;
  #pragma unroll
  for (int s = 0; s < 4; ++s)
    *(bf16x8*)(gb + s * 8) = *(const bf16x8*)(Cs + row * 72 + hh * 32 + s * 8);
}

// ---------------- fused attention+proj: per-window block, loop 6 heads ----------------
// 512 threads (8 waves), wave owns 16 query rows. Per head: QK^T -> bias+mask+exp -> Pl
// -> PV + MFMA-ones rowsum -> normalize -> Os -> proj-partial. 4 barriers/head.
// LDS: Kl 8K + Vt 8.5K + Pl 35K + Os 10K + Wp 12K = 73.5K -> 2 blocks/CU.
DEV void stage_head(const unsigned short* qkv, size_t qbase, int h,
                    const unsigned short* wp, unsigned short* Kl,
                    unsigned short* Vt, unsigned short* Wp,
                    int tid, int wave, int lane) {
  {  // K rows, XOR-swizzled slots
    int row = tid >> 2, slot = tid & 3;
    int m = (row + (row >> 2)) & 3;
    *(bf16x8*)(Kl + row * 32 + ((slot ^ m) * 8)) =
        *(const bf16x8*)(qkv + qbase + (size_t)row * 576 + 192 + h * 32 + slot * 8);
  }
  {  // V transposed
    int vtok = tid & 127, slot = tid >> 7;
    bf16x8 v = *(const bf16x8*)(qkv + qbase + (size_t)vtok * 576 + 384 + h * 32 + slot * 8);
    #pragma unroll
    for (int j = 0; j < 8; ++j) Vt[(slot * 8 + j) * 136 + vtok] = (unsigned short)v[j];
  }
  {  // wp slice [192 out][32 in], v4-W2 staging pattern
    int c = wave;
    int rg = c * 16 + (lane >> 2);
    gload16(wp + (size_t)rg * 192 + h * 32 + (((lane & 3) ^ ((rg >> 1) & 3)) * 8), Wp + c * 512);
    if (wave < 4) {
      int c2 = 8 + wave;
      int rg2 = c2 * 16 + (lane >> 2);
      gload16(wp + (size_t)rg2 * 192 + h * 32 + (((lane & 3) ^ ((rg2 >> 1) & 3)) * 8), Wp + c2 * 512);
    }
  }
}

__global__ __launch_bounds__(512, 4) void k_attnproj(
    const unsigned short* __restrict__ qkv, const float* __restrict__ bias6,
    const unsigned short* __restrict__ wp, const float* __restrict__ proj_b,
    const float* __restrict__ x, unsigned short* __restrict__ ybf) {
  __shared__ unsigned short Kl[128 * 32];
  __shared__ unsigned short Vt[32 * 136];
  __shared__ unsigned short Pl[128 * 140];
  __shared__ unsigned short Os[128 * 40];
  __shared__ unsigned short Wp[192 * 32];
  const int tid = threadIdx.x;
  const int wave = tid >> 6, lane = tid & 63;
  const int lrow = lane & 15, lk = lane >> 4;
  const int wIdx = ((int)blockIdx.x & 7) * 64 + ((int)blockIdx.x >> 3);
  const int widx = wIdx & 255;
  const int tw = widx >> 6, hw = (widx >> 3) & 7, ww = widx & 7;
  const size_t qbase = (size_t)wIdx * 73728;
  const float scale = 0.17677669529663687f;

  int rcol[8];
  #pragma unroll
  for (int tc = 0; tc < 8; ++tc) rcol[tc] = reg3(tw, hw, ww, tc * 16 + lrow);
  int rreg[4];
  #pragma unroll
  for (int j = 0; j < 4; ++j) rreg[j] = reg3(tw, hw, ww, wave * 16 + lk * 4 + j);

  bf16x8 ones;
  #pragma unroll
  for (int j = 0; j < 8; ++j) ones[j] = (short)0x3F80;

  stage_head(qkv, qbase, 0, wp, Kl, Vt, Wp, tid, wave, lane);

  f32x4 oaccP[12] = {};
  for (int h = 0; h < 6; ++h) {
    __syncthreads();   // B1: stage(h) visible

    // Q fragment for this head (wave's 16 rows)
    bf16x8 qf = *(const bf16x8*)(qkv + qbase + (size_t)(wave * 16 + lrow) * 576 +
                                 h * 32 + lk * 8);
    // S = Q @ K^T  (16 rows x 128 cols per wave)
    f32x4 s[8];
    #pragma unroll
    for (int tc = 0; tc < 8; ++tc) {
      int krow = tc * 16 + lrow;
      int m = (krow + (krow >> 2)) & 3;
      bf16x8 kf = *(const bf16x8*)(Kl + krow * 32 + ((lk ^ m) * 8));
      f32x4 z = {0.f, 0.f, 0.f, 0.f};
      s[tc] = __builtin_amdgcn_mfma_f32_16x16x32_bf16(qf, kf, z, 0, 0, 0);
    }

    // bias + mask + exp -> Pl (no-max softmax numerator)
    {
      const float* bp = bias6 + h * 16384 + wave * 2048 + lane * 32;
      f32x4 bb[8];
      #pragma unroll
      for (int tc = 0; tc < 8; ++tc) bb[tc] = *(const f32x4*)(bp + tc * 4);
      #pragma unroll
      for (int tc = 0; tc < 8; ++tc) {
        #pragma unroll
        for (int j = 0; j < 4; ++j) {
          float v = fmaf(s[tc][j], scale,
                         bb[tc][j] + ((rreg[j] == rcol[tc]) ? 0.0f : -100.0f));
          int row = wave * 16 + lk * 4 + j;
          Pl[row * 140 + tc * 16 + lrow] = f2bf(__expf(v));
        }
      }
    }
    __syncthreads();   // B2: Pl cross-lane RAW

    // O = P @ V ; rowsum via ones-column MFMA
    f32x4 o[2] = {};
    f32x4 osum = {};
    #pragma unroll
    for (int ks = 0; ks < 4; ++ks) {
      bf16x8 pa = *(const bf16x8*)(Pl + (wave * 16 + lrow) * 140 + ks * 32 + lk * 8);
      #pragma unroll
      for (int nc = 0; nc < 2; ++nc) {
        bf16x8 vb = *(const bf16x8*)(Vt + (nc * 16 + lrow) * 136 + ks * 32 + lk * 8);
        o[nc] = __builtin_amdgcn_mfma_f32_16x16x32_bf16(pa, vb, o[nc], 0, 0, 0);
      }
      osum = __builtin_amdgcn_mfma_f32_16x16x32_bf16(pa, ones, osum, 0, 0, 0);
    }
    // normalize -> Os[token][dim] (pad 40)
    #pragma unroll
    for (int j = 0; j < 4; ++j) {
      float rinv = __builtin_amdgcn_rcpf(osum[j]);
      int row = wave * 16 + lk * 4 + j;
      #pragma unroll
      for (int nc = 0; nc < 2; ++nc)
        Os[row * 40 + nc * 16 + lrow] = f2bf(o[nc][j] * rinv);
    }
    __syncthreads();   // B3: Os cross-lane RAW

    // proj partial: oaccP[ni] += O_h[16x32] @ wp_h^T  (v4 GEMM2 pattern)
    {
      bf16x8 af = *(const bf16x8*)(Os + (wave * 16 + lrow) * 40 + lk * 8);
      #pragma unroll
      for (int ni = 0; ni < 12; ++ni) {
        int n = ni * 16 + lrow;
        bf16x8 bv = *(const bf16x8*)(Wp + n * 32 + ((lk ^ ((n >> 1) & 3)) * 8));
        oaccP[ni] = __builtin_amdgcn_mfma_f32_16x16x32_bf16(af, bv, oaccP[ni], 0, 0, 0);
      }
    }
    __syncthreads();   // B4: all reads of head h done
    if (h < 5) stage_head(qkv, qbase, h + 1, wp, Kl, Vt, Wp, tid, wave, lane);
  }

  // epilogue: ybf = bf16(proj + proj_b + x)  (winmap scatter, natural order)
  size_t gf[4];
  #pragma unroll
  for (int j = 0; j < 4; ++j)
    gf[j] = winmap(wIdx * 128 + wave * 16 + lk * 4 + j) * 192;
  #pragma unroll
  for (int ni = 0; ni < 12; ++ni) {
    int col = ni * 16 + lrow;
    float bb = proj_b[col];
    #pragma unroll
    for (int j = 0; j < 4; ++j) {
      size_t idx = gf[j] + col;
      ybf[idx] = f2bf(oaccP[ni][j] + bb + x[idx]);
    }
  }
}

// ---------------- fused MLP v4 (known-good 67.7us): out = x + gelu(y@w1^T+b1)@w2^T + b2 ----
DEV void stage_w(const unsigned short* w1, const unsigned short* w2, int hb,
                 char* smem, int buf, int wave, int lane) {
  unsigned short* d1 = (unsigned short*)(smem + buf * 12288);
  unsigned short* d2 = (unsigned short*)(smem + 24576 + buf * 12288);
  const int l8 = lane >> 3, s8 = lane & 7;
  {
    int c = wave, p = c >> 2, q = c & 3;
    gload16(w1 + (size_t)(hb + q * 8 + l8) * 192 + p * 64 + ((s8 ^ l8) * 8), d1 + c * 512);
  }
  if (wave < 4) {
    int c = 8 + wave, p = c >> 2, q = c & 3;
    gload16(w1 + (size_t)(hb + q * 8 + l8) * 192 + p * 64 + ((s8 ^ l8) * 8), d1 + c * 512);
  }
  {
    int c = wave;
    int rg = c * 16 + (lane >> 2);
    gload16(w2 + (size_t)rg * 768 + hb + (((lane & 3) ^ ((rg >> 1) & 3)) * 8), d2 + c * 512);
  }
  if (wave < 4) {
    int c = 8 + wave;
    int rg = c * 16 + (lane >> 2);
    gload16(w2 + (size_t)rg * 768 + hb + (((lane & 3) ^ ((rg >> 1) & 3)) * 8), d2 + c * 512);
  }
}

__global__ __launch_bounds__(512, 4) void k_mlp(
    const unsigned short* __restrict__ y, const unsigned short* __restrict__ w1,
    const float* __restrict__ b1, const unsigned short* __restrict__ w2,
    const float* __restrict__ b2, const float* __restrict__ xin,
    float* __restrict__ out) {
  __shared__ char smem[57344];
  unsigned short* Hs = (unsigned short*)(smem + 49152);   // [128][32]
  const int tid = threadIdx.x;
  const int wave = tid >> 6, lane = tid & 63;
  const int lrow = lane & 15, lk = lane >> 4;
  const int m0 = (int)blockIdx.x * 128;
  const int tok = wave * 16 + lrow;
  const int tq = (lrow >> 1) & 3;

  bf16x8 yfr[6];
  {
    const unsigned short* yp = y + (size_t)(m0 + tok) * 192 + lk * 8;
    #pragma unroll
    for (int kk = 0; kk < 6; ++kk) yfr[kk] = *(const bf16x8*)(yp + kk * 32);
  }

  stage_w(w1, w2, 0, smem, 0, wave, lane);
  stage_w(w1, w2, 32, smem, 1, wave, lane);
  __syncthreads();

  f32x4 oacc[12] = {};
  for (int c = 0; c < 24; ++c) {
    const int hb = c * 32;
    unsigned short* w1b = (unsigned short*)(smem + (c & 1) * 12288);
    unsigned short* w2b = (unsigned short*)(smem + 24576 + (c & 1) * 12288);

    f32x4 hacc[2] = {};
    #pragma unroll
    for (int kk = 0; kk < 6; ++kk) {
      int p = kk >> 1, sc = (kk & 1) * 4;
      #pragma unroll
      for (int hi = 0; hi < 2; ++hi) {
        bf16x8 av = *(const bf16x8*)(w1b + p * 2048 + (hi * 16 + lrow) * 64 +
                                     (((sc + lk) ^ (lrow & 7)) * 8));
        hacc[hi] = __builtin_amdgcn_mfma_f32_16x16x32_bf16(av, yfr[kk], hacc[hi], 0, 0, 0);
      }
    }

    #pragma unroll
    for (int hi = 0; hi < 2; ++hi) {
      float4 bb = *(const float4*)(b1 + hb + hi * 16 + lk * 4);
      short2 p01 = pkbf(gelu_fast(hacc[hi][0] + bb.x), gelu_fast(hacc[hi][1] + bb.y));
      short2 p23 = pkbf(gelu_fast(hacc[hi][2] + bb.z), gelu_fast(hacc[hi][3] + bb.w));
      ushort4 o;
      o.x = (unsigned short)p01.x; o.y = (unsigned short)p01.y;
      o.z = (unsigned short)p23.x; o.w = (unsigned short)p23.y;
      int g = hi * 4 + lk;
      *(ushort4*)(Hs + tok * 32 + (((g >> 1) ^ tq) * 8) + (g & 1) * 4) = o;
    }

    {
      bf16x8 af = *(const bf16x8*)(Hs + tok * 32 + ((lk ^ tq) * 8));
      #pragma unroll
      for (int ni = 0; ni < 12; ++ni) {
        int n = ni * 16 + lrow;
        bf16x8 bv = *(const bf16x8*)(w2b + n * 32 + ((lk ^ ((n >> 1) & 3)) * 8));
        oacc[ni] = __builtin_amdgcn_mfma_f32_16x16x32_bf16(af, bv, oacc[ni], 0, 0, 0);
      }
    }

    __syncthreads();
    if (c < 22) stage_w(w1, w2, hb + 64, smem, c & 1, wave, lane);
  }

  #pragma unroll
  for (int ni = 0; ni < 12; ++ni) {
    int col = ni * 16 + lrow;
    float bb = b2[col];
    #pragma unroll
    for (int j = 0; j < 4; ++j) {
      size_t idx = (size_t)(m0 + wave * 16 + lk * 4 + j) * 192 + col;
      out[idx] = xin[idx] + oacc[ni][j] + bb;
    }
  }
}

// ---------------- launch ----------------
extern "C" void kernel_launch(void* const* d_in, const int* in_sizes, int n_in,
                              void* d_out, int out_size, void* d_ws, size_t ws_size,
                              hipStream_t stream) {
  const float* x      = (const float*)d_in[0];
  const float* qkv_w  = (const float*)d_in[2];
  const float* qkv_b  = (const float*)d_in[3];
  const float* proj_w = (const float*)d_in[4];
  const float* proj_b = (const float*)d_in[5];
  const float* rpb_t  = (const float*)d_in[6];
  const int*   rpb_i  = (const int*)d_in[7];
  const float* fc1_w  = (const float*)d_in[8];
  const float* fc1_b  = (const float*)d_in[9];
  const float* fc2_w  = (const float*)d_in[10];
  const float* fc2_b  = (const float*)d_in[11];
  float* out = (float*)d_out;
  char* ws = (char*)d_ws;

  unsigned short* qkv = (unsigned short*)(ws + 0);          // 65536x576 bf16
  unsigned short* ybf = (unsigned short*)(ws + 100663296);  // 65536x192 bf16
  unsigned short* wq  = (unsigned short*)(ws + 125829120);
  unsigned short* wp  = (unsigned short*)(ws + 126050304);
  unsigned short* w1  = (unsigned short*)(ws + 126124032);
  unsigned short* w2  = (unsigned short*)(ws + 126418944);
  float*          b6  = (float*)(ws + 126713856);

  k_prep<<<576, 256, 0, stream>>>(qkv_w, proj_w, fc1_w, fc2_w, rpb_t, rpb_i, wq, wp, w1, w2, b6);
  k_qkv<<<4608, 256, 0, stream>>>(x, wq, qkv_b, qkv);
  k_attnproj<<<512, 512, 0, stream>>>(qkv, b6, wp, proj_b, x, ybf);
  k_mlp<<<512, 512, 0, stream>>>(ybf, w1, fc1_b, w2, fc2_b, x, out);
}